// Round 4
// baseline (394.322 us; speedup 1.0000x reference)
//
#include <hip/hip_runtime.h>
#include <math.h>

#define IN_CHAN 4096
#define BATCH   16
#define NROWS   (3 * IN_CHAN)            // 12288 flat output rows (q,k,v stacked)
#define RPB     256                      // rows per K1 block (4 waves x 64 lanes)
#define NRG     (NROWS / RPB)            // 48 row-groups

#if __has_builtin(__builtin_amdgcn_exp2f)
#define EXP2F(x) __builtin_amdgcn_exp2f(x)
#else
#define EXP2F(x) exp2f(x)
#endif

// ---------------------------------------------------------------------------
// K1: partial QKV GEMV.  partial[ksb][r][b] = sum_{k in chunk} W[r][k]*x[b][k]
// 4 waves own 256 distinct rows (no cross-wave reduction). x chunk staged in
// LDS once per block; inner loop reads it via uniform-address ds_read_b128
// (HW broadcast, conflict-free, lgkm pipe) so the VMEM pipe carries ONLY the
// W stream: 1 KB contiguous per lane, double-buffered 8x float4 prefetch.
// ---------------------------------------------------------------------------
template <int KSB>
__global__ __launch_bounds__(256, 3) void k_qkv_partial(
    const float* __restrict__ x,
    const float* __restrict__ wq,
    const float* __restrict__ wk,
    const float* __restrict__ wv,
    float* __restrict__ partial)
{
    constexpr int KC     = IN_CHAN / KSB;  // k-range per block
    constexpr int CHUNKS = KC / 32;
    __shared__ float xs[BATCH][KC];

    const int bx  = blockIdx.x;            // NRG * KSB
    const int rg  = bx / KSB;
    const int ksb = bx % KSB;
    const int k0  = ksb * KC;
    const int r0  = rg * RPB;
    const int mat = r0 >> 12;              // block never straddles a matrix
    const float* __restrict__ W = (mat == 0) ? wq : (mat == 1) ? wk : wv;

    const int t = threadIdx.x;

    // ---- stage x[0..15][k0..k0+KC) -> LDS (linear, coalesced, conflict-free)
    constexpr int NQ = BATCH * KC / 4;     // total float4 quads
    float4* xsv = (float4*)&xs[0][0];
#pragma unroll
    for (int it = 0; it < NQ / 256; ++it) {
        const int fq = it * 256 + t;
        const int b  = fq / (KC / 4);
        const int qq = fq % (KC / 4);
        xsv[fq] = *(const float4*)(x + (size_t)b * IN_CHAN + k0 + qq * 4);
    }
    __syncthreads();

    const int wave = t >> 6, lane = t & 63;
    const int r = r0 + wave * 64 + lane;
    const int i = r & (IN_CHAN - 1);

    const float4* __restrict__ Wp =
        (const float4*)(W + (size_t)i * IN_CHAN + k0);

    float acc[BATCH];
#pragma unroll
    for (int b = 0; b < BATCH; ++b) acc[b] = 0.f;

    float4 wb[2][8];
#pragma unroll
    for (int u = 0; u < 8; ++u) wb[0][u] = Wp[u];
#pragma unroll
    for (int u = 0; u < 8; ++u) wb[1][u] = Wp[8 + u];

#pragma unroll 2                            // keeps wb[c&1] statically indexed
    for (int c = 0; c < CHUNKS; ++c) {
        const int cur = c & 1;
#pragma unroll
        for (int b = 0; b < BATCH; ++b) {
            float a = acc[b];
            const float* xrow = &xs[b][c * 32];
#pragma unroll
            for (int u = 0; u < 8; ++u) {
                const float4 xv = *(const float4*)(xrow + u * 4); // uniform bcast
                a = fmaf(wb[cur][u].x, xv.x, a);
                a = fmaf(wb[cur][u].y, xv.y, a);
                a = fmaf(wb[cur][u].z, xv.z, a);
                a = fmaf(wb[cur][u].w, xv.w, a);
            }
            acc[b] = a;
        }
        if (c + 2 < CHUNKS) {
#pragma unroll
            for (int u = 0; u < 8; ++u) wb[cur][u] = Wp[(c + 2) * 8 + u];
        }
    }

    // ---- store: lane writes 64B contiguous; wave writes 4KB contiguous
    float* dst = partial + ((size_t)ksb * NROWS + r) * BATCH;
#pragma unroll
    for (int g = 0; g < 4; ++g) {
        *(float4*)(dst + 4 * g) =
            make_float4(acc[4*g], acc[4*g+1], acc[4*g+2], acc[4*g+3]);
    }
}

// ---------------------------------------------------------------------------
// K1b: reduce ksb partials [p][r][b] -> qkv[mat][b][i], add bias,
// pre-scale k by log2(e).
// ---------------------------------------------------------------------------
__global__ __launch_bounds__(256) void k_qkv_reduce(
    const float* __restrict__ partial,
    const float* __restrict__ bq,
    const float* __restrict__ bk,
    const float* __restrict__ bv,
    float* __restrict__ qkv,
    int nksb)
{
    const int idx = blockIdx.x * 256 + threadIdx.x; // over NROWS*BATCH
    const int r = idx >> 4;
    const int b = idx & 15;
    float s = 0.f;
    for (int p = 0; p < nksb; ++p)
        s += partial[((size_t)p * NROWS + r) * BATCH + b];

    const int mat = r >> 12;
    const int i   = r & (IN_CHAN - 1);
    s += (mat == 0) ? bq[i] : (mat == 1) ? bk[i] : bv[i];
    if (mat == 1) s *= 1.44269504088896340736f;     // log2(e)
    qkv[((size_t)mat * BATCH + b) * IN_CHAN + i] = s;
}

// ---------------------------------------------------------------------------
// K2: rank-1 attention. out[b,i] = sum_j exp(q_i*k_j)*v_j / sum_j exp(q_i*k_j)
// Block = (b, 64 i's); k2,v staged in LDS (32 KB), read via uniform
// ds_read_b128 broadcast; 4 waves split j; LDS-reduce num/den.
// ---------------------------------------------------------------------------
__global__ __launch_bounds__(256) void k_attn(
    const float* __restrict__ qkv,
    float* __restrict__ out)
{
    __shared__ float ks[IN_CHAN];
    __shared__ float vs[IN_CHAN];
    __shared__ float red[2][4][64];

    const int b     = blockIdx.x >> 6;   // 16
    const int itile = blockIdx.x & 63;   // 64
    const int t     = threadIdx.x;

    const float* __restrict__ k2g = qkv + (size_t)(BATCH + b) * IN_CHAN;
    const float* __restrict__ vg  = qkv + (size_t)(2 * BATCH + b) * IN_CHAN;
#pragma unroll
    for (int it = 0; it < 4; ++it) {
        const int fq = it * 256 + t;
        ((float4*)ks)[fq] = ((const float4*)k2g)[fq];
        ((float4*)vs)[fq] = ((const float4*)vg)[fq];
    }
    __syncthreads();

    const int wave = t >> 6, lane = t & 63;
    const int i = itile * 64 + lane;
    const float q = qkv[(size_t)b * IN_CHAN + i];

    float num0 = 0.f, num1 = 0.f, num2 = 0.f, num3 = 0.f;
    float den0 = 0.f, den1 = 0.f, den2 = 0.f, den3 = 0.f;

    const int j0 = wave * (IN_CHAN / 4);
    for (int j = j0; j < j0 + IN_CHAN / 4; j += 8) {
        const float4 ka = *(const float4*)&ks[j];
        const float4 kb = *(const float4*)&ks[j + 4];
        const float4 va = *(const float4*)&vs[j];
        const float4 vb = *(const float4*)&vs[j + 4];
        const float e0 = EXP2F(q * ka.x);
        const float e1 = EXP2F(q * ka.y);
        const float e2 = EXP2F(q * ka.z);
        const float e3 = EXP2F(q * ka.w);
        const float e4 = EXP2F(q * kb.x);
        const float e5 = EXP2F(q * kb.y);
        const float e6 = EXP2F(q * kb.z);
        const float e7 = EXP2F(q * kb.w);
        num0 = fmaf(e0, va.x, num0); den0 += e0;
        num1 = fmaf(e1, va.y, num1); den1 += e1;
        num2 = fmaf(e2, va.z, num2); den2 += e2;
        num3 = fmaf(e3, va.w, num3); den3 += e3;
        num0 = fmaf(e4, vb.x, num0); den0 += e4;
        num1 = fmaf(e5, vb.y, num1); den1 += e5;
        num2 = fmaf(e6, vb.z, num2); den2 += e6;
        num3 = fmaf(e7, vb.w, num3); den3 += e7;
    }

    red[0][wave][lane] = (num0 + num1) + (num2 + num3);
    red[1][wave][lane] = (den0 + den1) + (den2 + den3);
    __syncthreads();
    if (wave == 0) {
        const float n = (red[0][0][lane] + red[0][1][lane]) +
                        (red[0][2][lane] + red[0][3][lane]);
        const float d = (red[1][0][lane] + red[1][1][lane]) +
                        (red[1][2][lane] + red[1][3][lane]);
        out[(size_t)b * IN_CHAN + i] = n / d;
    }
}

// ---------------------------------------------------------------------------
extern "C" void kernel_launch(void* const* d_in, const int* in_sizes, int n_in,
                              void* d_out, int out_size, void* d_ws, size_t ws_size,
                              hipStream_t stream)
{
    const float* x  = (const float*)d_in[0];
    const float* wq = (const float*)d_in[1];
    const float* bq = (const float*)d_in[2];
    const float* wk = (const float*)d_in[3];
    const float* bk = (const float*)d_in[4];
    const float* wv = (const float*)d_in[5];
    const float* bv = (const float*)d_in[6];
    float* out = (float*)d_out;

    const size_t qkv_f = (size_t)3 * BATCH * IN_CHAN;
    auto need = [&](int K) { return ((size_t)K * NROWS * BATCH + qkv_f) * 4; };
    const int ksb = (ws_size >= need(16)) ? 16 : (ws_size >= need(8)) ? 8 : 4;

    float* partial = (float*)d_ws;
    float* qkv     = partial + (size_t)ksb * NROWS * BATCH;

    if (ksb == 16)
        k_qkv_partial<16><<<NRG * 16, 256, 0, stream>>>(x, wq, wk, wv, partial);
    else if (ksb == 8)
        k_qkv_partial<8><<<NRG * 8, 256, 0, stream>>>(x, wq, wk, wv, partial);
    else
        k_qkv_partial<4><<<NRG * 4, 256, 0, stream>>>(x, wq, wk, wv, partial);

    k_qkv_reduce<<<(NROWS * BATCH) / 256, 256, 0, stream>>>(
        partial, bq, bk, bv, qkv, ksb);
    k_attn<<<BATCH * 64, 256, 0, stream>>>(qkv, out);
}

// Round 5
// 296.637 us; speedup vs baseline: 1.3293x; 1.3293x over previous
//
#include <hip/hip_runtime.h>
#include <math.h>

#define IN_CHAN 4096
#define BATCH   16
#define NROWS   (3 * IN_CHAN)   // 12288 flat output rows (q,k,v stacked)
#define RPB     512             // rows per K1 block (8 waves x 64 lanes)
#define NRG     (NROWS / RPB)   // 24 row-groups

#if __has_builtin(__builtin_amdgcn_exp2f)
#define EXP2F(x) __builtin_amdgcn_exp2f(x)
#else
#define EXP2F(x) exp2f(x)
#endif

// ---------------------------------------------------------------------------
// K1: partial QKV GEMV.  partial[ksb][r][b] = sum_{k in chunk} W[r][k]*x[b][k]
// Thread t owns row r0+t (waves split ROWS; the whole block shares one
// k-range, so x addresses depend only on blockIdx + loop constants ->
// compiler emits scalar s_load for x: the 16x batch reuse rides the scalar
// pipe, VMEM carries only the W stream).  W: each lane streams KC*4 B
// contiguous as 128-B line-aligned groups of 8 float4, double-buffered,
// FULLY unrolled (all buffer indices static -> no scratch).
// ---------------------------------------------------------------------------
template <int KSB>
__global__ __launch_bounds__(512, 4) void k_qkv_partial(
    const float* __restrict__ x,
    const float* __restrict__ wq,
    const float* __restrict__ wk,
    const float* __restrict__ wv,
    float* __restrict__ partial)
{
    constexpr int KC  = IN_CHAN / KSB;  // k per block
    constexpr int NCH = KC / 32;        // 128-B groups per lane

    const int bx  = blockIdx.x;         // NRG * KSB
    const int rg  = bx / KSB;
    const int ksb = bx % KSB;
    const int k0  = ksb * KC;           // block-uniform
    const int r0  = rg * RPB;
    const int mat = r0 >> 12;           // block never straddles a matrix
    const float* __restrict__ W = (mat == 0) ? wq : (mat == 1) ? wk : wv;

    const int t = threadIdx.x;
    const int i = (r0 + t) & (IN_CHAN - 1);
    const float4* __restrict__ Wp =
        (const float4*)(W + (size_t)i * IN_CHAN + k0);

    float acc[BATCH];
#pragma unroll
    for (int b = 0; b < BATCH; ++b) acc[b] = 0.f;

    float4 bufA[8], bufB[8];

#define PREFETCH(BUF, g)                                        \
    {                                                           \
        _Pragma("unroll")                                       \
        for (int u = 0; u < 8; ++u) BUF[u] = Wp[(g) * 8 + u];   \
    }

#define COMPUTE(BUF, c)                                         \
    {                                                           \
        _Pragma("unroll")                                       \
        for (int b = 0; b < BATCH; ++b) {                       \
            const float* __restrict__ xb =                      \
                x + (size_t)b * IN_CHAN + k0 + (c) * 32;        \
            float a = acc[b];                                   \
            _Pragma("unroll")                                   \
            for (int u = 0; u < 8; ++u) {                       \
                a = fmaf(BUF[u].x, xb[u * 4 + 0], a);           \
                a = fmaf(BUF[u].y, xb[u * 4 + 1], a);           \
                a = fmaf(BUF[u].z, xb[u * 4 + 2], a);           \
                a = fmaf(BUF[u].w, xb[u * 4 + 3], a);           \
            }                                                   \
            acc[b] = a;                                         \
        }                                                       \
    }

    PREFETCH(bufA, 0);
    PREFETCH(bufB, 1);
#pragma unroll
    for (int c = 0; c < NCH; ++c) {      // FULL unroll: everything static
        if ((c & 1) == 0) {
            COMPUTE(bufA, c);
            if (c + 2 < NCH) PREFETCH(bufA, c + 2);
        } else {
            COMPUTE(bufB, c);
            if (c + 2 < NCH) PREFETCH(bufB, c + 2);
        }
    }
#undef PREFETCH
#undef COMPUTE

    // lane writes 64 B contiguous; wave covers 4 KB contiguous
    float* dst = partial + ((size_t)ksb * NROWS + r0 + t) * BATCH;
#pragma unroll
    for (int g = 0; g < 4; ++g)
        *(float4*)(dst + 4 * g) =
            make_float4(acc[4*g], acc[4*g+1], acc[4*g+2], acc[4*g+3]);
}

// ---------------------------------------------------------------------------
// K1b: reduce ksb partials [p][r][b] -> qkv[mat][b][i], add bias,
// pre-scale k by log2(e) so K2 can use native v_exp_f32 (2^x).
// ---------------------------------------------------------------------------
__global__ __launch_bounds__(256) void k_qkv_reduce(
    const float* __restrict__ partial,
    const float* __restrict__ bq,
    const float* __restrict__ bk,
    const float* __restrict__ bv,
    float* __restrict__ qkv,
    int nksb)
{
    const int idx = blockIdx.x * 256 + threadIdx.x; // over NROWS*BATCH
    const int r = idx >> 4;
    const int b = idx & 15;
    float s = 0.f;
    for (int p = 0; p < nksb; ++p)
        s += partial[((size_t)p * NROWS + r) * BATCH + b];

    const int mat = r >> 12;
    const int i   = r & (IN_CHAN - 1);
    s += (mat == 0) ? bq[i] : (mat == 1) ? bk[i] : bv[i];
    if (mat == 1) s *= 1.44269504088896340736f;     // log2(e)
    qkv[((size_t)mat * BATCH + b) * IN_CHAN + i] = s;
}

// ---------------------------------------------------------------------------
// K2: rank-1 attention. out[b,i] = sum_j exp(q_i*k_j)*v_j / sum_j exp(q_i*k_j)
// Block = (b, 64 i's) x 8 waves; wave w covers j-slice [w*512, w*512+512).
// readfirstlane forces the j-slice base into an SGPR so k/v loads are
// scalar (wave-uniform addresses). LDS-reduce the 8 wave partials.
// ---------------------------------------------------------------------------
__global__ __launch_bounds__(512) void k_attn(
    const float* __restrict__ qkv,
    float* __restrict__ out)
{
    const int b     = blockIdx.x >> 6;   // 16
    const int itile = blockIdx.x & 63;   // 64
    const int wave  = __builtin_amdgcn_readfirstlane(threadIdx.x >> 6); // 8
    const int lane  = threadIdx.x & 63;
    const int i     = itile * 64 + lane;

    const float q = qkv[(size_t)b * IN_CHAN + i];
    const float* __restrict__ k2 =
        qkv + (size_t)(BATCH + b) * IN_CHAN + wave * 512;
    const float* __restrict__ vv =
        qkv + (size_t)(2 * BATCH + b) * IN_CHAN + wave * 512;

    float num[4], den[4];
#pragma unroll
    for (int u = 0; u < 4; ++u) { num[u] = 0.f; den[u] = 0.f; }

    for (int j = 0; j < 512; j += 16) {   // 32 iterations
#pragma unroll
        for (int g = 0; g < 4; ++g) {
            const float4 kv = *(const float4*)(k2 + j + g * 4); // s_load
            const float4 vf = *(const float4*)(vv + j + g * 4); // s_load
            const float e0 = EXP2F(q * kv.x);
            const float e1 = EXP2F(q * kv.y);
            const float e2 = EXP2F(q * kv.z);
            const float e3 = EXP2F(q * kv.w);
            num[g] = fmaf(e0, vf.x, num[g]); den[g] += e0;
            num[g] = fmaf(e1, vf.y, num[g]); den[g] += e1;
            num[g] = fmaf(e2, vf.z, num[g]); den[g] += e2;
            num[g] = fmaf(e3, vf.w, num[g]); den[g] += e3;
        }
    }

    __shared__ float red[2][8][64];
    red[0][wave][lane] = (num[0] + num[1]) + (num[2] + num[3]);
    red[1][wave][lane] = (den[0] + den[1]) + (den[2] + den[3]);
    __syncthreads();
    if (wave == 0) {
        float n = 0.f, d = 0.f;
#pragma unroll
        for (int w = 0; w < 8; ++w) {
            n += red[0][w][lane];
            d += red[1][w][lane];
        }
        out[(size_t)b * IN_CHAN + i] = n / d;
    }
}

// ---------------------------------------------------------------------------
extern "C" void kernel_launch(void* const* d_in, const int* in_sizes, int n_in,
                              void* d_out, int out_size, void* d_ws, size_t ws_size,
                              hipStream_t stream)
{
    const float* x  = (const float*)d_in[0];
    const float* wq = (const float*)d_in[1];
    const float* bq = (const float*)d_in[2];
    const float* wk = (const float*)d_in[3];
    const float* bk = (const float*)d_in[4];
    const float* wv = (const float*)d_in[5];
    const float* bv = (const float*)d_in[6];
    float* out = (float*)d_out;

    const size_t qkv_f = (size_t)3 * BATCH * IN_CHAN;
    auto need = [&](int K) { return ((size_t)K * NROWS * BATCH + qkv_f) * 4; };
    const int ksb = (ws_size >= need(32)) ? 32
                  : (ws_size >= need(16)) ? 16 : 8;

    float* partial = (float*)d_ws;
    float* qkv     = partial + (size_t)ksb * NROWS * BATCH;

    if (ksb == 32)
        k_qkv_partial<32><<<NRG * 32, 512, 0, stream>>>(x, wq, wk, wv, partial);
    else if (ksb == 16)
        k_qkv_partial<16><<<NRG * 16, 512, 0, stream>>>(x, wq, wk, wv, partial);
    else
        k_qkv_partial<8><<<NRG * 8, 512, 0, stream>>>(x, wq, wk, wv, partial);

    k_qkv_reduce<<<(NROWS * BATCH) / 256, 256, 0, stream>>>(
        partial, bq, bk, bv, qkv, ksb);
    k_attn<<<BATCH * 64, 512, 0, stream>>>(qkv, out);
}